// Round 5
// baseline (66.878 us; speedup 1.0000x reference)
//
#include <hip/hip_runtime.h>
#include <hip/hip_bf16.h>
#include <hip/hip_cooperative_groups.h>
#include <math.h>

namespace cg = cooperative_groups;

namespace {
constexpr int GD = 64;
constexpr int GK = 32;
constexpr float LOG2PI_F = 1.8378770664093454f;

typedef __attribute__((ext_vector_type(8))) short bf16x8;
typedef __attribute__((ext_vector_type(4))) float f32x4;

__device__ __forceinline__ short f2bf(float f) {
  __hip_bfloat16 h = __float2bfloat16(f);  // pairs into v_cvt_pk_bf16_f32
  return __builtin_bit_cast(short, h);
}

__device__ __forceinline__ float4 sq4(const float4 a) {
  return make_float4(a.x * a.x, a.y * a.y, a.z * a.z, a.w * a.w);
}

__device__ __forceinline__ bf16x8 pack8(const float4 a, const float4 b) {
  bf16x8 r;
  r[0] = f2bf(a.x); r[1] = f2bf(a.y); r[2] = f2bf(a.z); r[3] = f2bf(a.w);
  r[4] = f2bf(b.x); r[5] = f2bf(b.y); r[6] = f2bf(b.z); r[7] = f2bf(b.w);
  return r;
}

// Single cooperative kernel. Wave = 32 rows (2 16-row tiles). SWAPPED operands:
// D = W(16 comps x 32 feat) * X(32 feat x 16 rows):
//   A-frag (weights): lane l holds comp row l&15, k=(l>>4)*8+j  == frag[s][g][c]
//   B-frag (x):       lane l holds x-row col l&15, k=(l>>4)*8+j == same x loads as before
//   D: col = lane&15 = x-row, row = (lane>>4)*4+reg = component  -> LSE is lane-local.
__global__ __launch_bounds__(256, 2) void gmm_one(
    const float* __restrict__ x, const float* __restrict__ theta,
    const int* __restrict__ fds, float* __restrict__ ws,
    float* __restrict__ out, float gterm, int n, int nblk) {
  __shared__ bf16x8 frag[4][4][32];  // [s][g][c]: s=0,1 -> mu*iv lo/hi dims; s=2,3 -> -0.5*iv
  __shared__ float pls[8][32];
  __shared__ float pmm[8][32];
  __shared__ float Asm[GK];
  __shared__ float bred[4];

  const int t = threadIdx.x;
  const int lane = t & 63;
  const int wave = t >> 6;
  const int c1 = lane & 15;
  const int g = lane >> 4;

  // ---- x loads first; HBM latency hides under the fold ----
  const int base = blockIdx.x * 128 + wave * 32;
  const int rA = base + c1;
  const int rB = base + 16 + c1;
  const size_t oA = (size_t)(rA < n ? rA : n - 1) * GD;
  const size_t oB = (size_t)(rB < n ? rB : n - 1) * GD;
  const int dlo = g * 8;
  const int dhi = 32 + g * 8;
  const float4 xA0 = *(const float4*)(x + oA + dlo);
  const float4 xA1 = *(const float4*)(x + oA + dlo + 4);
  const float4 xA2 = *(const float4*)(x + oA + dhi);
  const float4 xA3 = *(const float4*)(x + oA + dhi + 4);
  const float4 xB0 = *(const float4*)(x + oB + dlo);
  const float4 xB1 = *(const float4*)(x + oB + dlo + 4);
  const float4 xB2 = *(const float4*)(x + oB + dhi);
  const float4 xB3 = *(const float4*)(x + oB + dhi + 4);

  // ---- cooperative fold: thread t -> col c=t&31, 8 dims ----
  {
    const int c = t & 31;
    const int gh = t >> 5;
    const int gg = gh & 3;
    const int hf = gh >> 2;
    const int d0 = hf * 32 + gg * 8;
    const float* __restrict__ mu = theta + GK + c * GD + d0;
    const float* __restrict__ sg = theta + GK + GK * GD + c * GD + d0;
    const float4 m0 = *(const float4*)(mu);
    const float4 m1 = *(const float4*)(mu + 4);
    const float4 s0 = *(const float4*)(sg);
    const float4 s1 = *(const float4*)(sg + 4);
    const float mv[8] = {m0.x, m0.y, m0.z, m0.w, m1.x, m1.y, m1.z, m1.w};
    const float sv[8] = {s0.x, s0.y, s0.z, s0.w, s1.x, s1.y, s1.z, s1.w};
    bf16x8 f1, f2;
    float ls = 0.f, mm = 0.f;
#pragma unroll
    for (int j = 0; j < 8; ++j) {
      const float iv = __builtin_amdgcn_rcpf(sv[j] * sv[j]);
      const float l = __logf(sv[j]);
      ls += l;
      mm = fmaf(mv[j] * mv[j], iv, mm);
      f1[j] = f2bf(mv[j] * iv);
      f2[j] = f2bf(-0.5f * iv);
    }
    frag[hf][gg][c] = f1;
    frag[hf + 2][gg][c] = f2;
    pls[gh][c] = ls;
    pmm[gh][c] = mm;
  }
  __syncthreads();
  if (t < GK) {
    float ls = 0.f, mm = 0.f;
#pragma unroll
    for (int i = 0; i < 8; ++i) { ls += pls[i][t]; mm += pmm[i][t]; }
    Asm[t] = __logf(theta[t]) - ls - 0.5f * GD * LOG2PI_F - 0.5f * mm;
  }
  __syncthreads();

  // ---- weights = A-operands, register-resident ----
  const bf16x8 W0l = frag[0][g][c1], W0h = frag[0][g][c1 + 16];
  const bf16x8 W1l = frag[1][g][c1], W1h = frag[1][g][c1 + 16];
  const bf16x8 W2l = frag[2][g][c1], W2h = frag[2][g][c1 + 16];
  const bf16x8 W3l = frag[3][g][c1], W3h = frag[3][g][c1 + 16];
  float asl[4], ash[4];
#pragma unroll
  for (int j = 0; j < 4; ++j) {
    asl[j] = Asm[g * 4 + j];       // comps this lane owns in D0
    ash[j] = Asm[16 + g * 4 + j];  // comps in D1
  }

  // ---- B-fragments (x rows) + 16 MFMAs ----
  const bf16x8 bA0 = pack8(xA0, xA1);
  const bf16x8 bA1 = pack8(xA2, xA3);
  const bf16x8 bA2 = pack8(sq4(xA0), sq4(xA1));
  const bf16x8 bA3 = pack8(sq4(xA2), sq4(xA3));
  const bf16x8 bB0 = pack8(xB0, xB1);
  const bf16x8 bB1 = pack8(xB2, xB3);
  const bf16x8 bB2 = pack8(sq4(xB0), sq4(xB1));
  const bf16x8 bB3 = pack8(sq4(xB2), sq4(xB3));
  f32x4 DA0 = {0.f, 0.f, 0.f, 0.f}, DA1 = {0.f, 0.f, 0.f, 0.f};
  f32x4 DB0 = {0.f, 0.f, 0.f, 0.f}, DB1 = {0.f, 0.f, 0.f, 0.f};
  DA0 = __builtin_amdgcn_mfma_f32_16x16x32_bf16(W0l, bA0, DA0, 0, 0, 0);
  DA1 = __builtin_amdgcn_mfma_f32_16x16x32_bf16(W0h, bA0, DA1, 0, 0, 0);
  DB0 = __builtin_amdgcn_mfma_f32_16x16x32_bf16(W0l, bB0, DB0, 0, 0, 0);
  DB1 = __builtin_amdgcn_mfma_f32_16x16x32_bf16(W0h, bB0, DB1, 0, 0, 0);
  DA0 = __builtin_amdgcn_mfma_f32_16x16x32_bf16(W1l, bA1, DA0, 0, 0, 0);
  DA1 = __builtin_amdgcn_mfma_f32_16x16x32_bf16(W1h, bA1, DA1, 0, 0, 0);
  DB0 = __builtin_amdgcn_mfma_f32_16x16x32_bf16(W1l, bB1, DB0, 0, 0, 0);
  DB1 = __builtin_amdgcn_mfma_f32_16x16x32_bf16(W1h, bB1, DB1, 0, 0, 0);
  DA0 = __builtin_amdgcn_mfma_f32_16x16x32_bf16(W2l, bA2, DA0, 0, 0, 0);
  DA1 = __builtin_amdgcn_mfma_f32_16x16x32_bf16(W2h, bA2, DA1, 0, 0, 0);
  DB0 = __builtin_amdgcn_mfma_f32_16x16x32_bf16(W2l, bB2, DB0, 0, 0, 0);
  DB1 = __builtin_amdgcn_mfma_f32_16x16x32_bf16(W2h, bB2, DB1, 0, 0, 0);
  DA0 = __builtin_amdgcn_mfma_f32_16x16x32_bf16(W3l, bA3, DA0, 0, 0, 0);
  DA1 = __builtin_amdgcn_mfma_f32_16x16x32_bf16(W3h, bA3, DA1, 0, 0, 0);
  DB0 = __builtin_amdgcn_mfma_f32_16x16x32_bf16(W3l, bB3, DB0, 0, 0, 0);
  DB1 = __builtin_amdgcn_mfma_f32_16x16x32_bf16(W3h, bB3, DB1, 0, 0, 0);

  // ---- lane-local LSE (8 comps/lane), cross-g combine via 2+2 shuffles ----
  auto lse_of = [&](const f32x4& D0, const f32x4& D1) -> float {
    const float e0 = D0[0] + asl[0], e1 = D0[1] + asl[1];
    const float e2 = D0[2] + asl[2], e3 = D0[3] + asl[3];
    const float e4 = D1[0] + ash[0], e5 = D1[1] + ash[1];
    const float e6 = D1[2] + ash[2], e7 = D1[3] + ash[3];
    float m = fmaxf(fmaxf(fmaxf(e0, e1), fmaxf(e2, e3)),
                    fmaxf(fmaxf(e4, e5), fmaxf(e6, e7)));
    m = fmaxf(m, __shfl_xor(m, 16));
    m = fmaxf(m, __shfl_xor(m, 32));
    float e = (__expf(e0 - m) + __expf(e1 - m)) + (__expf(e2 - m) + __expf(e3 - m)) +
              (__expf(e4 - m) + __expf(e5 - m)) + (__expf(e6 - m) + __expf(e7 - m));
    e += __shfl_xor(e, 16);
    e += __shfl_xor(e, 32);
    return m + __logf(e);
  };
  const float lA = lse_of(DA0, DA1);
  const float lB = lse_of(DB0, DB1);
  float v = (g == 0) ? ((rA < n ? lA : 0.f) + (rB < n ? lB : 0.f)) : 0.f;
  v += __shfl_xor(v, 1);
  v += __shfl_xor(v, 2);
  v += __shfl_xor(v, 4);
  v += __shfl_xor(v, 8);
  if (lane == 0) bred[wave] = v;
  __syncthreads();
  if (t == 0) ws[blockIdx.x] = (bred[0] + bred[1]) + (bred[2] + bred[3]);
  __threadfence();

  cg::this_grid().sync();

  // ---- block 0: final reduce + priors + write ----
  if (blockIdx.x == 0) {
    float acc = 0.f;
    for (int i = t; i < nblk; i += 256) acc += ws[i];
    acc *= (float)fds[0] / (float)n;
    const int k = t >> 3, jj = t & 7;
    float pr = 0.f;
#pragma unroll
    for (int i = 0; i < 8; ++i) {
      const int idx = k * GD + jj * 8 + i;
      const float mu = theta[GK + idx];
      const float sgv = theta[GK + GK * GD + idx];
      const float ls = __logf(sgv);
      pr += -0.5f * mu * mu - ls - 0.5f * ls * ls - LOG2PI_F;
    }
    if (jj == 0) pr += 999.0f * __logf(theta[k]);  // (ALPHA0-1)*log p
    acc += pr;
    float* red = &pls[0][0];  // reuse LDS
    red[t] = acc;
    __syncthreads();
    for (int off = 128; off > 0; off >>= 1) {
      if (t < off) red[t] += red[t + off];
      __syncthreads();
    }
    if (t == 0) out[0] = red[0] + gterm;
  }
}
}  // namespace

extern "C" void kernel_launch(void* const* d_in, const int* in_sizes, int n_in,
                              void* d_out, int out_size, void* d_ws, size_t ws_size,
                              hipStream_t stream) {
  const float* x = (const float*)d_in[0];
  const float* theta = (const float*)d_in[1];
  const int* fds = (const int*)d_in[2];
  float* out = (float*)d_out;
  float* ws = (float*)d_ws;
  int n = in_sizes[0] / GD;             // 50000
  int nblk = (n + 127) / 128;           // 128 rows per block -> 391 blocks
  // gammaln(K*a) - K*gammaln(a): constant of the problem shape, computed on HOST
  float gterm = (float)(lgamma(32.0 * 1000.0) - 32.0 * lgamma(1000.0));

  void* args[] = {(void*)&x, (void*)&theta, (void*)&fds, (void*)&ws,
                  (void*)&out, (void*)&gterm, (void*)&n, (void*)&nblk};
  hipLaunchCooperativeKernel((const void*)gmm_one, dim3(nblk), dim3(256),
                             args, 0, stream);
}

// Round 6
// 18.209 us; speedup vs baseline: 3.6729x; 3.6729x over previous
//
#include <hip/hip_runtime.h>
#include <hip/hip_bf16.h>
#include <math.h>

namespace {
constexpr int GD = 64;
constexpr int GK = 32;
constexpr float LOG2PI_F = 1.8378770664093454f;

typedef __attribute__((ext_vector_type(8))) short bf16x8;
typedef __attribute__((ext_vector_type(4))) float f32x4;

__device__ __forceinline__ short f2bf(float f) {
  __hip_bfloat16 h = __float2bfloat16(f);  // pairs into v_cvt_pk_bf16_f32
  return __builtin_bit_cast(short, h);
}

__device__ __forceinline__ float4 sq4(const float4 a) {
  return make_float4(a.x * a.x, a.y * a.y, a.z * a.z, a.w * a.w);
}

__device__ __forceinline__ bf16x8 pack8(const float4 a, const float4 b) {
  bf16x8 r;
  r[0] = f2bf(a.x); r[1] = f2bf(a.y); r[2] = f2bf(a.z); r[3] = f2bf(a.w);
  r[4] = f2bf(b.x); r[5] = f2bf(b.y); r[6] = f2bf(b.z); r[7] = f2bf(b.w);
  return r;
}

// Single kernel, atomic accumulation into out (pre-zeroed by hipMemsetAsync).
// Wave = 32 rows (2 16-row tiles). SWAPPED operands: D = W(16comp x 32feat) * X(32feat x 16row)
//   A-frag (weights): lane l holds comp l&15, k=(l>>4)*8+j  == frag[s][g][c]
//   B-frag (x rows):  lane l holds row l&15,  k=(l>>4)*8+j
//   D: col = lane&15 = x-row, row = (lane>>4)*4+reg = component -> LSE is lane-local.
// (Layout validated by round-5 pass, absmax 0.)
__global__ __launch_bounds__(256) void gmm_fused(
    const float* __restrict__ x, const float* __restrict__ theta,
    const int* __restrict__ fds, float* __restrict__ out,
    float gterm, int n) {
  __shared__ bf16x8 frag[4][4][32];  // [s][g][c]: s=0,1 -> mu*iv lo/hi dims; s=2,3 -> -0.5*iv
  __shared__ float pls[8][32];
  __shared__ float pmm[8][32];
  __shared__ float Asm[GK];
  __shared__ float bred[4];
  __shared__ float pprior[4];

  const int t = threadIdx.x;
  const int lane = t & 63;
  const int wave = t >> 6;
  const int c1 = lane & 15;
  const int g = lane >> 4;

  // ---- x loads first; HBM latency hides under the fold ----
  const int base = blockIdx.x * 128 + wave * 32;
  const int rA = base + c1;
  const int rB = base + 16 + c1;
  const size_t oA = (size_t)(rA < n ? rA : n - 1) * GD;
  const size_t oB = (size_t)(rB < n ? rB : n - 1) * GD;
  const int dlo = g * 8;
  const int dhi = 32 + g * 8;
  const float4 xA0 = *(const float4*)(x + oA + dlo);
  const float4 xA1 = *(const float4*)(x + oA + dlo + 4);
  const float4 xA2 = *(const float4*)(x + oA + dhi);
  const float4 xA3 = *(const float4*)(x + oA + dhi + 4);
  const float4 xB0 = *(const float4*)(x + oB + dlo);
  const float4 xB1 = *(const float4*)(x + oB + dlo + 4);
  const float4 xB2 = *(const float4*)(x + oB + dhi);
  const float4 xB3 = *(const float4*)(x + oB + dhi + 4);

  // ---- cooperative fold: thread t -> col c=t&31, 8 dims ----
  {
    const int c = t & 31;
    const int gh = t >> 5;
    const int gg = gh & 3;
    const int hf = gh >> 2;
    const int d0 = hf * 32 + gg * 8;
    const float* __restrict__ mu = theta + GK + c * GD + d0;
    const float* __restrict__ sg = theta + GK + GK * GD + c * GD + d0;
    const float4 m0 = *(const float4*)(mu);
    const float4 m1 = *(const float4*)(mu + 4);
    const float4 s0 = *(const float4*)(sg);
    const float4 s1 = *(const float4*)(sg + 4);
    const float mv[8] = {m0.x, m0.y, m0.z, m0.w, m1.x, m1.y, m1.z, m1.w};
    const float sv[8] = {s0.x, s0.y, s0.z, s0.w, s1.x, s1.y, s1.z, s1.w};
    bf16x8 f1, f2;
    float ls = 0.f, mm = 0.f;
#pragma unroll
    for (int j = 0; j < 8; ++j) {
      const float iv = __builtin_amdgcn_rcpf(sv[j] * sv[j]);
      const float l = __logf(sv[j]);
      ls += l;
      mm = fmaf(mv[j] * mv[j], iv, mm);
      f1[j] = f2bf(mv[j] * iv);
      f2[j] = f2bf(-0.5f * iv);
    }
    frag[hf][gg][c] = f1;
    frag[hf + 2][gg][c] = f2;
    pls[gh][c] = ls;
    pmm[gh][c] = mm;
  }
  // block 0 also computes the mu/sigma/p priors (concurrent with other blocks' rows)
  if (blockIdx.x == 0) {
    const int k = t >> 3, jj = t & 7;
    float pr = 0.f;
#pragma unroll
    for (int i = 0; i < 8; ++i) {
      const int idx = k * GD + jj * 8 + i;
      const float mu = theta[GK + idx];
      const float sgv = theta[GK + GK * GD + idx];
      const float ls = __logf(sgv);
      pr += -0.5f * mu * mu - ls - 0.5f * ls * ls - LOG2PI_F;
    }
    if (jj == 0) pr += 999.0f * __logf(theta[k]);  // (ALPHA0-1)*log p
#pragma unroll
    for (int off = 1; off < 64; off <<= 1) pr += __shfl_xor(pr, off);
    if (lane == 0) pprior[wave] = pr;
  }
  __syncthreads();
  if (t < GK) {
    float ls = 0.f, mm = 0.f;
#pragma unroll
    for (int i = 0; i < 8; ++i) { ls += pls[i][t]; mm += pmm[i][t]; }
    Asm[t] = __logf(theta[t]) - ls - 0.5f * GD * LOG2PI_F - 0.5f * mm;
  }
  __syncthreads();

  // ---- weights = A-operands, register-resident ----
  const bf16x8 W0l = frag[0][g][c1], W0h = frag[0][g][c1 + 16];
  const bf16x8 W1l = frag[1][g][c1], W1h = frag[1][g][c1 + 16];
  const bf16x8 W2l = frag[2][g][c1], W2h = frag[2][g][c1 + 16];
  const bf16x8 W3l = frag[3][g][c1], W3h = frag[3][g][c1 + 16];
  float asl[4], ash[4];
#pragma unroll
  for (int j = 0; j < 4; ++j) {
    asl[j] = Asm[g * 4 + j];
    ash[j] = Asm[16 + g * 4 + j];
  }

  // ---- B-fragments (x rows) + 16 MFMAs ----
  const bf16x8 bA0 = pack8(xA0, xA1);
  const bf16x8 bA1 = pack8(xA2, xA3);
  const bf16x8 bA2 = pack8(sq4(xA0), sq4(xA1));
  const bf16x8 bA3 = pack8(sq4(xA2), sq4(xA3));
  const bf16x8 bB0 = pack8(xB0, xB1);
  const bf16x8 bB1 = pack8(xB2, xB3);
  const bf16x8 bB2 = pack8(sq4(xB0), sq4(xB1));
  const bf16x8 bB3 = pack8(sq4(xB2), sq4(xB3));
  f32x4 DA0 = {0.f, 0.f, 0.f, 0.f}, DA1 = {0.f, 0.f, 0.f, 0.f};
  f32x4 DB0 = {0.f, 0.f, 0.f, 0.f}, DB1 = {0.f, 0.f, 0.f, 0.f};
  DA0 = __builtin_amdgcn_mfma_f32_16x16x32_bf16(W0l, bA0, DA0, 0, 0, 0);
  DA1 = __builtin_amdgcn_mfma_f32_16x16x32_bf16(W0h, bA0, DA1, 0, 0, 0);
  DB0 = __builtin_amdgcn_mfma_f32_16x16x32_bf16(W0l, bB0, DB0, 0, 0, 0);
  DB1 = __builtin_amdgcn_mfma_f32_16x16x32_bf16(W0h, bB0, DB1, 0, 0, 0);
  DA0 = __builtin_amdgcn_mfma_f32_16x16x32_bf16(W1l, bA1, DA0, 0, 0, 0);
  DA1 = __builtin_amdgcn_mfma_f32_16x16x32_bf16(W1h, bA1, DA1, 0, 0, 0);
  DB0 = __builtin_amdgcn_mfma_f32_16x16x32_bf16(W1l, bB1, DB0, 0, 0, 0);
  DB1 = __builtin_amdgcn_mfma_f32_16x16x32_bf16(W1h, bB1, DB1, 0, 0, 0);
  DA0 = __builtin_amdgcn_mfma_f32_16x16x32_bf16(W2l, bA2, DA0, 0, 0, 0);
  DA1 = __builtin_amdgcn_mfma_f32_16x16x32_bf16(W2h, bA2, DA1, 0, 0, 0);
  DB0 = __builtin_amdgcn_mfma_f32_16x16x32_bf16(W2l, bB2, DB0, 0, 0, 0);
  DB1 = __builtin_amdgcn_mfma_f32_16x16x32_bf16(W2h, bB2, DB1, 0, 0, 0);
  DA0 = __builtin_amdgcn_mfma_f32_16x16x32_bf16(W3l, bA3, DA0, 0, 0, 0);
  DA1 = __builtin_amdgcn_mfma_f32_16x16x32_bf16(W3h, bA3, DA1, 0, 0, 0);
  DB0 = __builtin_amdgcn_mfma_f32_16x16x32_bf16(W3l, bB3, DB0, 0, 0, 0);
  DB1 = __builtin_amdgcn_mfma_f32_16x16x32_bf16(W3h, bB3, DB1, 0, 0, 0);

  // ---- lane-local LSE (8 comps/lane), cross-g combine via 2+2 shuffles ----
  auto lse_of = [&](const f32x4& D0, const f32x4& D1) -> float {
    const float e0 = D0[0] + asl[0], e1 = D0[1] + asl[1];
    const float e2 = D0[2] + asl[2], e3 = D0[3] + asl[3];
    const float e4 = D1[0] + ash[0], e5 = D1[1] + ash[1];
    const float e6 = D1[2] + ash[2], e7 = D1[3] + ash[3];
    float m = fmaxf(fmaxf(fmaxf(e0, e1), fmaxf(e2, e3)),
                    fmaxf(fmaxf(e4, e5), fmaxf(e6, e7)));
    m = fmaxf(m, __shfl_xor(m, 16));
    m = fmaxf(m, __shfl_xor(m, 32));
    float e = (__expf(e0 - m) + __expf(e1 - m)) + (__expf(e2 - m) + __expf(e3 - m)) +
              (__expf(e4 - m) + __expf(e5 - m)) + (__expf(e6 - m) + __expf(e7 - m));
    e += __shfl_xor(e, 16);
    e += __shfl_xor(e, 32);
    return m + __logf(e);
  };
  const float lA = lse_of(DA0, DA1);
  const float lB = lse_of(DB0, DB1);
  float v = (g == 0) ? ((rA < n ? lA : 0.f) + (rB < n ? lB : 0.f)) : 0.f;
  v += __shfl_xor(v, 1);
  v += __shfl_xor(v, 2);
  v += __shfl_xor(v, 4);
  v += __shfl_xor(v, 8);
  if (lane == 0) bred[wave] = v;
  __syncthreads();
  if (t == 0) {
    float acc = ((bred[0] + bred[1]) + (bred[2] + bred[3])) *
                ((float)fds[0] / (float)n);
    if (blockIdx.x == 0)
      acc += (pprior[0] + pprior[1]) + (pprior[2] + pprior[3]) + gterm;
    atomicAdd(out, acc);
  }
}
}  // namespace

extern "C" void kernel_launch(void* const* d_in, const int* in_sizes, int n_in,
                              void* d_out, int out_size, void* d_ws, size_t ws_size,
                              hipStream_t stream) {
  const float* x = (const float*)d_in[0];
  const float* theta = (const float*)d_in[1];
  const int* fds = (const int*)d_in[2];
  float* out = (float*)d_out;
  const int n = in_sizes[0] / GD;     // 50000
  const int nblk = (n + 127) / 128;   // 128 rows per block -> 391 blocks
  // gammaln(K*a) - K*gammaln(a): constant of the problem shape, computed on HOST
  const float gterm = (float)(lgamma(32.0 * 1000.0) - 32.0 * lgamma(1000.0));

  hipMemsetAsync(out, 0, sizeof(float), stream);
  gmm_fused<<<nblk, 256, 0, stream>>>(x, theta, fds, out, gterm, n);
}

// Round 7
// 12.734 us; speedup vs baseline: 5.2521x; 1.4300x over previous
//
#include <hip/hip_runtime.h>
#include <hip/hip_bf16.h>
#include <math.h>

namespace {
constexpr int GD = 64;
constexpr int GK = 32;
constexpr float LOG2PI_F = 1.8378770664093454f;

typedef __attribute__((ext_vector_type(8))) short bf16x8;
typedef __attribute__((ext_vector_type(4))) float f32x4;

__device__ __forceinline__ short f2bf(float f) {
  __hip_bfloat16 h = __float2bfloat16(f);  // pairs into v_cvt_pk_bf16_f32
  return __builtin_bit_cast(short, h);
}

__device__ __forceinline__ float4 sq4(const float4 a) {
  return make_float4(a.x * a.x, a.y * a.y, a.z * a.z, a.w * a.w);
}

__device__ __forceinline__ bf16x8 pack8(const float4 a, const float4 b) {
  bf16x8 r;
  r[0] = f2bf(a.x); r[1] = f2bf(a.y); r[2] = f2bf(a.z); r[3] = f2bf(a.w);
  r[4] = f2bf(b.x); r[5] = f2bf(b.y); r[6] = f2bf(b.z); r[7] = f2bf(b.w);
  return r;
}

// Main kernel: 256 rows/block (4 waves x 4 row-tiles of 16), 196 blocks -> one
// block-round over the 256 CUs. SWAPPED operands (validated round 5/6, absmax 0):
//   D = W(16 comps x 32 feat) * X(32 feat x 16 rows)
//   A-frag (weights): lane l holds comp l&15, k=(l>>4)*8+j == frag[s][g][c]
//   B-frag (x rows):  lane l holds row l&15,  k=(l>>4)*8+j
//   D: col = lane&15 = x-row, row = (lane>>4)*4+reg = comp -> LSE lane-local.
// Per-block partial -> ws[blk]; tail kernel reduces + priors + overwrites out.
__global__ __launch_bounds__(256) void gmm_main(
    const float* __restrict__ x, const float* __restrict__ theta,
    float* __restrict__ ws, int n) {
  __shared__ bf16x8 frag[4][4][32];  // [s][g][c]: s=0,1 -> mu*iv lo/hi; s=2,3 -> -0.5*iv
  __shared__ float pls[8][32];
  __shared__ float pmm[8][32];
  __shared__ float Asm[GK];
  __shared__ float bred[4];

  const int t = threadIdx.x;
  const int lane = t & 63;
  const int wave = t >> 6;
  const int c1 = lane & 15;
  const int g = lane >> 4;
  const int dlo = g * 8;
  const int dhi = 32 + g * 8;

  // ---- issue all 16 x-loads up front; HBM latency hides under the fold ----
  const int base = blockIdx.x * 256 + wave * 64;
  float4 xv[4][4];
#pragma unroll
  for (int tt = 0; tt < 4; ++tt) {
    const int r = base + tt * 16 + c1;
    const size_t o = (size_t)(r < n ? r : n - 1) * GD;  // clamp; masked at the sum
    xv[tt][0] = *(const float4*)(x + o + dlo);
    xv[tt][1] = *(const float4*)(x + o + dlo + 4);
    xv[tt][2] = *(const float4*)(x + o + dhi);
    xv[tt][3] = *(const float4*)(x + o + dhi + 4);
  }

  // ---- cooperative fold: thread t -> col c=t&31, 8 dims ----
  {
    const int c = t & 31;
    const int gh = t >> 5;
    const int gg = gh & 3;
    const int hf = gh >> 2;
    const int d0 = hf * 32 + gg * 8;
    const float* __restrict__ mu = theta + GK + c * GD + d0;
    const float* __restrict__ sg = theta + GK + GK * GD + c * GD + d0;
    const float4 m0 = *(const float4*)(mu);
    const float4 m1 = *(const float4*)(mu + 4);
    const float4 s0 = *(const float4*)(sg);
    const float4 s1 = *(const float4*)(sg + 4);
    const float mv[8] = {m0.x, m0.y, m0.z, m0.w, m1.x, m1.y, m1.z, m1.w};
    const float sv[8] = {s0.x, s0.y, s0.z, s0.w, s1.x, s1.y, s1.z, s1.w};
    bf16x8 f1, f2;
    float ls = 0.f, mm = 0.f;
#pragma unroll
    for (int j = 0; j < 8; ++j) {
      const float iv = __builtin_amdgcn_rcpf(sv[j] * sv[j]);
      const float l = __logf(sv[j]);
      ls += l;
      mm = fmaf(mv[j] * mv[j], iv, mm);
      f1[j] = f2bf(mv[j] * iv);
      f2[j] = f2bf(-0.5f * iv);
    }
    frag[hf][gg][c] = f1;
    frag[hf + 2][gg][c] = f2;
    pls[gh][c] = ls;
    pmm[gh][c] = mm;
  }
  __syncthreads();
  if (t < GK) {
    float ls = 0.f, mm = 0.f;
#pragma unroll
    for (int i = 0; i < 8; ++i) { ls += pls[i][t]; mm += pmm[i][t]; }
    Asm[t] = __logf(theta[t]) - ls - 0.5f * GD * LOG2PI_F - 0.5f * mm;
  }
  __syncthreads();

  // ---- weights = A-operands, register-resident ----
  const bf16x8 W0l = frag[0][g][c1], W0h = frag[0][g][c1 + 16];
  const bf16x8 W1l = frag[1][g][c1], W1h = frag[1][g][c1 + 16];
  const bf16x8 W2l = frag[2][g][c1], W2h = frag[2][g][c1 + 16];
  const bf16x8 W3l = frag[3][g][c1], W3h = frag[3][g][c1 + 16];
  float asl[4], ash[4];
#pragma unroll
  for (int j = 0; j < 4; ++j) {
    asl[j] = Asm[g * 4 + j];
    ash[j] = Asm[16 + g * 4 + j];
  }

  // ---- per-tile: B-fragments + 8 MFMAs; then lane-local LSE ----
  float rowacc = 0.f;
#pragma unroll
  for (int tt = 0; tt < 4; ++tt) {
    const bf16x8 b0 = pack8(xv[tt][0], xv[tt][1]);
    const bf16x8 b1 = pack8(xv[tt][2], xv[tt][3]);
    const bf16x8 b2 = pack8(sq4(xv[tt][0]), sq4(xv[tt][1]));
    const bf16x8 b3 = pack8(sq4(xv[tt][2]), sq4(xv[tt][3]));
    f32x4 D0 = {0.f, 0.f, 0.f, 0.f};
    f32x4 D1 = {0.f, 0.f, 0.f, 0.f};
    D0 = __builtin_amdgcn_mfma_f32_16x16x32_bf16(W0l, b0, D0, 0, 0, 0);
    D1 = __builtin_amdgcn_mfma_f32_16x16x32_bf16(W0h, b0, D1, 0, 0, 0);
    D0 = __builtin_amdgcn_mfma_f32_16x16x32_bf16(W1l, b1, D0, 0, 0, 0);
    D1 = __builtin_amdgcn_mfma_f32_16x16x32_bf16(W1h, b1, D1, 0, 0, 0);
    D0 = __builtin_amdgcn_mfma_f32_16x16x32_bf16(W2l, b2, D0, 0, 0, 0);
    D1 = __builtin_amdgcn_mfma_f32_16x16x32_bf16(W2h, b2, D1, 0, 0, 0);
    D0 = __builtin_amdgcn_mfma_f32_16x16x32_bf16(W3l, b3, D0, 0, 0, 0);
    D1 = __builtin_amdgcn_mfma_f32_16x16x32_bf16(W3h, b3, D1, 0, 0, 0);

    const float e0 = D0[0] + asl[0], e1 = D0[1] + asl[1];
    const float e2 = D0[2] + asl[2], e3 = D0[3] + asl[3];
    const float e4 = D1[0] + ash[0], e5 = D1[1] + ash[1];
    const float e6 = D1[2] + ash[2], e7 = D1[3] + ash[3];
    float m = fmaxf(fmaxf(fmaxf(e0, e1), fmaxf(e2, e3)),
                    fmaxf(fmaxf(e4, e5), fmaxf(e6, e7)));
    m = fmaxf(m, __shfl_xor(m, 16));
    m = fmaxf(m, __shfl_xor(m, 32));
    float e = (__expf(e0 - m) + __expf(e1 - m)) + (__expf(e2 - m) + __expf(e3 - m)) +
              (__expf(e4 - m) + __expf(e5 - m)) + (__expf(e6 - m) + __expf(e7 - m));
    e += __shfl_xor(e, 16);
    e += __shfl_xor(e, 32);
    const int r = base + tt * 16 + c1;
    rowacc += (r < n) ? (m + __logf(e)) : 0.f;
  }

  // ---- block reduction: g==0 lanes hold complete per-row sums ----
  float v = (g == 0) ? rowacc : 0.f;
  v += __shfl_xor(v, 1);
  v += __shfl_xor(v, 2);
  v += __shfl_xor(v, 4);
  v += __shfl_xor(v, 8);
  if (lane == 0) bred[wave] = v;
  __syncthreads();
  if (t == 0) ws[blockIdx.x] = (bred[0] + bred[1]) + (bred[2] + bred[3]);
}

// 1-block tail: sum per-block partials, scale, add priors, overwrite out.
__global__ __launch_bounds__(256) void gmm_tail(const float* __restrict__ theta,
                                                const int* __restrict__ fds,
                                                const float* __restrict__ ws,
                                                float* __restrict__ out,
                                                float gterm, int n, int nblk) {
  const int t = threadIdx.x;
  float acc = 0.f;
  for (int i = t; i < nblk; i += 256) acc += ws[i];
  acc *= (float)fds[0] / (float)n;
  const int k = t >> 3, jj = t & 7;
  float pr = 0.f;
#pragma unroll
  for (int i = 0; i < 8; ++i) {
    const int idx = k * GD + jj * 8 + i;
    const float mu = theta[GK + idx];
    const float sgv = theta[GK + GK * GD + idx];
    const float ls = __logf(sgv);
    pr += -0.5f * mu * mu - ls - 0.5f * ls * ls - LOG2PI_F;
  }
  if (jj == 0) pr += 999.0f * __logf(theta[k]);  // (ALPHA0-1)*log p
  acc += pr;
  __shared__ float red[256];
  red[t] = acc;
  __syncthreads();
  for (int off = 128; off > 0; off >>= 1) {
    if (t < off) red[t] += red[t + off];
    __syncthreads();
  }
  if (t == 0) out[0] = red[0] + gterm;
}
}  // namespace

extern "C" void kernel_launch(void* const* d_in, const int* in_sizes, int n_in,
                              void* d_out, int out_size, void* d_ws, size_t ws_size,
                              hipStream_t stream) {
  const float* x = (const float*)d_in[0];
  const float* theta = (const float*)d_in[1];
  const int* fds = (const int*)d_in[2];
  float* out = (float*)d_out;
  float* ws = (float*)d_ws;
  const int n = in_sizes[0] / GD;     // 50000
  const int nblk = (n + 255) / 256;   // 256 rows/block -> 196 blocks (one round on 256 CUs)
  // gammaln(K*a) - K*gammaln(a): constant of the problem shape, computed on HOST
  const float gterm = (float)(lgamma(32.0 * 1000.0) - 32.0 * lgamma(1000.0));

  gmm_main<<<nblk, 256, 0, stream>>>(x, theta, ws, n);
  gmm_tail<<<1, 256, 0, stream>>>(theta, fds, ws, out, gterm, n, nblk);
}

// Round 8
// 12.425 us; speedup vs baseline: 5.3824x; 1.0248x over previous
//
#include <hip/hip_runtime.h>
#include <hip/hip_bf16.h>
#include <math.h>

namespace {
constexpr int GD = 64;
constexpr int GK = 32;
constexpr float LOG2PI_F = 1.8378770664093454f;

typedef __attribute__((ext_vector_type(8))) short bf16x8;
typedef __attribute__((ext_vector_type(4))) float f32x4;

__device__ __forceinline__ short f2bf(float f) {
  __hip_bfloat16 h = __float2bfloat16(f);  // pairs into v_cvt_pk_bf16_f32
  return __builtin_bit_cast(short, h);
}

__device__ __forceinline__ float4 sq4(const float4 a) {
  return make_float4(a.x * a.x, a.y * a.y, a.z * a.z, a.w * a.w);
}

__device__ __forceinline__ bf16x8 pack8(const float4 a, const float4 b) {
  bf16x8 r;
  r[0] = f2bf(a.x); r[1] = f2bf(a.y); r[2] = f2bf(a.z); r[3] = f2bf(a.w);
  r[4] = f2bf(b.x); r[5] = f2bf(b.y); r[6] = f2bf(b.z); r[7] = f2bf(b.w);
  return r;
}

// Main kernel: 512 threads (8 waves) x 32 rows/wave = 256 rows/block, 196 blocks
// -> 2 waves/SIMD on every CU (latency hiding) with the fold done ONCE per block
// by threads 0..255. Theta loads issue BEFORE x loads so the fold's s_waitcnt
// only covers its own 4 loads (vmcnt retires in issue order).
// SWAPPED operands (validated rounds 5-7, absmax 0):
//   D = W(16 comps x 32 feat) * X(32 feat x 16 rows)
//   A-frag (weights): lane l holds comp l&15, k=(l>>4)*8+j == frag[s][g][c]
//   B-frag (x rows):  lane l holds row l&15,  k=(l>>4)*8+j
//   D: col = lane&15 = x-row, row = (lane>>4)*4+reg = comp -> LSE lane-local.
__global__ __launch_bounds__(512) void gmm_main(
    const float* __restrict__ x, const float* __restrict__ theta,
    float* __restrict__ ws, int n) {
  __shared__ bf16x8 frag[4][4][32];  // [s][g][c]: s=0,1 -> mu*iv lo/hi; s=2,3 -> -0.5*iv
  __shared__ float pls[8][32];
  __shared__ float pmm[8][32];
  __shared__ float Asm[GK];
  __shared__ float bred[8];

  const int t = threadIdx.x;
  const int lane = t & 63;
  const int wave = t >> 6;
  const int c1 = lane & 15;
  const int g = lane >> 4;
  const int dlo = g * 8;
  const int dhi = 32 + g * 8;
  const bool folder = (t < 256);

  // ---- theta loads FIRST (fold inputs; smallest latency-to-use) ----
  float4 m0, m1, s0, s1;
  int c = 0, gh = 0;
  if (folder) {
    c = t & 31;
    gh = t >> 5;
    const int d0 = (gh >> 2) * 32 + (gh & 3) * 8;
    const float* __restrict__ mu = theta + GK + c * GD + d0;
    const float* __restrict__ sg = theta + GK + GK * GD + c * GD + d0;
    m0 = *(const float4*)(mu);
    m1 = *(const float4*)(mu + 4);
    s0 = *(const float4*)(sg);
    s1 = *(const float4*)(sg + 4);
  }

  // ---- x loads (2 row-tiles per wave) ----
  const int base = blockIdx.x * 256 + wave * 32;
  const int rA = base + c1;
  const int rB = base + 16 + c1;
  const size_t oA = (size_t)(rA < n ? rA : n - 1) * GD;  // clamp; masked at the sum
  const size_t oB = (size_t)(rB < n ? rB : n - 1) * GD;
  const float4 xA0 = *(const float4*)(x + oA + dlo);
  const float4 xA1 = *(const float4*)(x + oA + dlo + 4);
  const float4 xA2 = *(const float4*)(x + oA + dhi);
  const float4 xA3 = *(const float4*)(x + oA + dhi + 4);
  const float4 xB0 = *(const float4*)(x + oB + dlo);
  const float4 xB1 = *(const float4*)(x + oB + dlo + 4);
  const float4 xB2 = *(const float4*)(x + oB + dhi);
  const float4 xB3 = *(const float4*)(x + oB + dhi + 4);

  // ---- cooperative fold (threads 0..255): col c, 8 dims each ----
  if (folder) {
    const float mv[8] = {m0.x, m0.y, m0.z, m0.w, m1.x, m1.y, m1.z, m1.w};
    const float sv[8] = {s0.x, s0.y, s0.z, s0.w, s1.x, s1.y, s1.z, s1.w};
    bf16x8 f1, f2;
    float ls = 0.f, mm = 0.f;
#pragma unroll
    for (int j = 0; j < 8; ++j) {
      const float iv = __builtin_amdgcn_rcpf(sv[j] * sv[j]);
      const float l = __logf(sv[j]);
      ls += l;
      mm = fmaf(mv[j] * mv[j], iv, mm);
      f1[j] = f2bf(mv[j] * iv);
      f2[j] = f2bf(-0.5f * iv);
    }
    const int gg = gh & 3;
    const int hf = gh >> 2;
    frag[hf][gg][c] = f1;
    frag[hf + 2][gg][c] = f2;
    pls[gh][c] = ls;
    pmm[gh][c] = mm;
  }
  __syncthreads();
  if (t < GK) {
    float ls = 0.f, mm = 0.f;
#pragma unroll
    for (int i = 0; i < 8; ++i) { ls += pls[i][t]; mm += pmm[i][t]; }
    Asm[t] = __logf(theta[t]) - ls - 0.5f * GD * LOG2PI_F - 0.5f * mm;
  }
  __syncthreads();

  // ---- weights = A-operands, register-resident ----
  const bf16x8 W0l = frag[0][g][c1], W0h = frag[0][g][c1 + 16];
  const bf16x8 W1l = frag[1][g][c1], W1h = frag[1][g][c1 + 16];
  const bf16x8 W2l = frag[2][g][c1], W2h = frag[2][g][c1 + 16];
  const bf16x8 W3l = frag[3][g][c1], W3h = frag[3][g][c1 + 16];
  float asl[4], ash[4];
#pragma unroll
  for (int j = 0; j < 4; ++j) {
    asl[j] = Asm[g * 4 + j];
    ash[j] = Asm[16 + g * 4 + j];
  }

  // ---- B-fragments (x rows) + 16 MFMAs ----
  const bf16x8 bA0 = pack8(xA0, xA1);
  const bf16x8 bA1 = pack8(xA2, xA3);
  const bf16x8 bA2 = pack8(sq4(xA0), sq4(xA1));
  const bf16x8 bA3 = pack8(sq4(xA2), sq4(xA3));
  const bf16x8 bB0 = pack8(xB0, xB1);
  const bf16x8 bB1 = pack8(xB2, xB3);
  const bf16x8 bB2 = pack8(sq4(xB0), sq4(xB1));
  const bf16x8 bB3 = pack8(sq4(xB2), sq4(xB3));
  f32x4 DA0 = {0.f, 0.f, 0.f, 0.f}, DA1 = {0.f, 0.f, 0.f, 0.f};
  f32x4 DB0 = {0.f, 0.f, 0.f, 0.f}, DB1 = {0.f, 0.f, 0.f, 0.f};
  DA0 = __builtin_amdgcn_mfma_f32_16x16x32_bf16(W0l, bA0, DA0, 0, 0, 0);
  DA1 = __builtin_amdgcn_mfma_f32_16x16x32_bf16(W0h, bA0, DA1, 0, 0, 0);
  DB0 = __builtin_amdgcn_mfma_f32_16x16x32_bf16(W0l, bB0, DB0, 0, 0, 0);
  DB1 = __builtin_amdgcn_mfma_f32_16x16x32_bf16(W0h, bB0, DB1, 0, 0, 0);
  DA0 = __builtin_amdgcn_mfma_f32_16x16x32_bf16(W1l, bA1, DA0, 0, 0, 0);
  DA1 = __builtin_amdgcn_mfma_f32_16x16x32_bf16(W1h, bA1, DA1, 0, 0, 0);
  DB0 = __builtin_amdgcn_mfma_f32_16x16x32_bf16(W1l, bB1, DB0, 0, 0, 0);
  DB1 = __builtin_amdgcn_mfma_f32_16x16x32_bf16(W1h, bB1, DB1, 0, 0, 0);
  DA0 = __builtin_amdgcn_mfma_f32_16x16x32_bf16(W2l, bA2, DA0, 0, 0, 0);
  DA1 = __builtin_amdgcn_mfma_f32_16x16x32_bf16(W2h, bA2, DA1, 0, 0, 0);
  DB0 = __builtin_amdgcn_mfma_f32_16x16x32_bf16(W2l, bB2, DB0, 0, 0, 0);
  DB1 = __builtin_amdgcn_mfma_f32_16x16x32_bf16(W2h, bB2, DB1, 0, 0, 0);
  DA0 = __builtin_amdgcn_mfma_f32_16x16x32_bf16(W3l, bA3, DA0, 0, 0, 0);
  DA1 = __builtin_amdgcn_mfma_f32_16x16x32_bf16(W3h, bA3, DA1, 0, 0, 0);
  DB0 = __builtin_amdgcn_mfma_f32_16x16x32_bf16(W3l, bB3, DB0, 0, 0, 0);
  DB1 = __builtin_amdgcn_mfma_f32_16x16x32_bf16(W3h, bB3, DB1, 0, 0, 0);

  // ---- lane-local LSE (8 comps/lane), cross-g combine via 2+2 shuffles ----
  auto lse_of = [&](const f32x4& D0, const f32x4& D1) -> float {
    const float e0 = D0[0] + asl[0], e1 = D0[1] + asl[1];
    const float e2 = D0[2] + asl[2], e3 = D0[3] + asl[3];
    const float e4 = D1[0] + ash[0], e5 = D1[1] + ash[1];
    const float e6 = D1[2] + ash[2], e7 = D1[3] + ash[3];
    float m = fmaxf(fmaxf(fmaxf(e0, e1), fmaxf(e2, e3)),
                    fmaxf(fmaxf(e4, e5), fmaxf(e6, e7)));
    m = fmaxf(m, __shfl_xor(m, 16));
    m = fmaxf(m, __shfl_xor(m, 32));
    float e = (__expf(e0 - m) + __expf(e1 - m)) + (__expf(e2 - m) + __expf(e3 - m)) +
              (__expf(e4 - m) + __expf(e5 - m)) + (__expf(e6 - m) + __expf(e7 - m));
    e += __shfl_xor(e, 16);
    e += __shfl_xor(e, 32);
    return m + __logf(e);
  };
  const float lA = lse_of(DA0, DA1);
  const float lB = lse_of(DB0, DB1);
  float v = (g == 0) ? ((rA < n ? lA : 0.f) + (rB < n ? lB : 0.f)) : 0.f;
  v += __shfl_xor(v, 1);
  v += __shfl_xor(v, 2);
  v += __shfl_xor(v, 4);
  v += __shfl_xor(v, 8);
  if (lane == 0) bred[wave] = v;
  __syncthreads();
  if (t == 0) {
    float s = 0.f;
#pragma unroll
    for (int i = 0; i < 8; ++i) s += bred[i];
    ws[blockIdx.x] = s;
  }
}

// 1-block tail: sum per-block partials, scale, add priors, overwrite out.
__global__ __launch_bounds__(256) void gmm_tail(const float* __restrict__ theta,
                                                const int* __restrict__ fds,
                                                const float* __restrict__ ws,
                                                float* __restrict__ out,
                                                float gterm, int n, int nblk) {
  const int t = threadIdx.x;
  float acc = 0.f;
  for (int i = t; i < nblk; i += 256) acc += ws[i];
  acc *= (float)fds[0] / (float)n;
  const int k = t >> 3, jj = t & 7;
  float pr = 0.f;
#pragma unroll
  for (int i = 0; i < 8; ++i) {
    const int idx = k * GD + jj * 8 + i;
    const float mu = theta[GK + idx];
    const float sgv = theta[GK + GK * GD + idx];
    const float ls = __logf(sgv);
    pr += -0.5f * mu * mu - ls - 0.5f * ls * ls - LOG2PI_F;
  }
  if (jj == 0) pr += 999.0f * __logf(theta[k]);  // (ALPHA0-1)*log p
  acc += pr;
  __shared__ float red[256];
  red[t] = acc;
  __syncthreads();
  for (int off = 128; off > 0; off >>= 1) {
    if (t < off) red[t] += red[t + off];
    __syncthreads();
  }
  if (t == 0) out[0] = red[0] + gterm;
}
}  // namespace

extern "C" void kernel_launch(void* const* d_in, const int* in_sizes, int n_in,
                              void* d_out, int out_size, void* d_ws, size_t ws_size,
                              hipStream_t stream) {
  const float* x = (const float*)d_in[0];
  const float* theta = (const float*)d_in[1];
  const int* fds = (const int*)d_in[2];
  float* out = (float*)d_out;
  float* ws = (float*)d_ws;
  const int n = in_sizes[0] / GD;     // 50000
  const int nblk = (n + 255) / 256;   // 256 rows/block -> 196 blocks, 512 thr each
  // gammaln(K*a) - K*gammaln(a): constant of the problem shape, computed on HOST
  const float gterm = (float)(lgamma(32.0 * 1000.0) - 32.0 * lgamma(1000.0));

  gmm_main<<<nblk, 512, 0, stream>>>(x, theta, ws, n);
  gmm_tail<<<1, 256, 0, stream>>>(theta, fds, ws, out, gterm, n, nblk);
}

// Round 9
// 11.330 us; speedup vs baseline: 5.9029x; 1.0967x over previous
//
#include <hip/hip_runtime.h>
#include <hip/hip_bf16.h>
#include <math.h>

namespace {
constexpr int GD = 64;
constexpr int GK = 32;
constexpr float LOG2PI_F = 1.8378770664093454f;

typedef __attribute__((ext_vector_type(8))) short bf16x8;
typedef __attribute__((ext_vector_type(4))) float f32x4;

__device__ __forceinline__ short f2bf(float f) {
  __hip_bfloat16 h = __float2bfloat16(f);  // pairs into v_cvt_pk_bf16_f32
  return __builtin_bit_cast(short, h);
}

__device__ __forceinline__ float4 sq4(const float4 a) {
  return make_float4(a.x * a.x, a.y * a.y, a.z * a.z, a.w * a.w);
}

__device__ __forceinline__ bf16x8 pack8(const float4 a, const float4 b) {
  bf16x8 r;
  r[0] = f2bf(a.x); r[1] = f2bf(a.y); r[2] = f2bf(a.z); r[3] = f2bf(a.w);
  r[4] = f2bf(b.x); r[5] = f2bf(b.y); r[6] = f2bf(b.z); r[7] = f2bf(b.w);
  return r;
}

// Main kernel: 1024 threads (16 waves) x 16 rows/wave = 256 rows/block, 196 blocks
// -> 4 waves/SIMD. Fold done once per block by threads 0..255 (theta loads issued
// before x loads so the fold's waitcnt doesn't cover the x stream). Block 0 also
// computes the mu/sigma/p priors FROM THE SAME REGISTERS the fold loaded (zero
// extra global traffic) -> ws[nblk]. SWAPPED operands (validated r5-r8, absmax 0):
//   D = W(16 comps x 32 feat) * X(32 feat x 16 rows)
//   A-frag (weights): lane l holds comp l&15, k=(l>>4)*8+j == frag[s][g][c]
//   B-frag (x rows):  lane l holds row l&15,  k=(l>>4)*8+j
//   D: col = lane&15 = x-row, row = (lane>>4)*4+reg = comp -> LSE lane-local.
__global__ __launch_bounds__(1024) void gmm_main(
    const float* __restrict__ x, const float* __restrict__ theta,
    float* __restrict__ ws, int n, int nblk) {
  __shared__ bf16x8 frag[4][4][32];  // [s][g][c]: s=0,1 -> mu*iv lo/hi; s=2,3 -> -0.5*iv
  __shared__ float pls[8][32];
  __shared__ float pmm[8][32];
  __shared__ float Asm[GK];
  __shared__ float bred[16];
  __shared__ float pprior[5];  // [0..3]: mu/sigma terms per folder wave; [4]: p term

  const int t = threadIdx.x;
  const int lane = t & 63;
  const int wave = t >> 6;
  const int c1 = lane & 15;
  const int g = lane >> 4;
  const int dlo = g * 8;
  const int dhi = 32 + g * 8;
  const bool folder = (t < 256);

  // ---- theta loads FIRST (fold inputs; vmcnt retires in issue order) ----
  float4 m0, m1, s0, s1;
  int c = 0, gh = 0;
  if (folder) {
    c = t & 31;
    gh = t >> 5;
    const int d0 = (gh >> 2) * 32 + (gh & 3) * 8;
    const float* __restrict__ mu = theta + GK + c * GD + d0;
    const float* __restrict__ sg = theta + GK + GK * GD + c * GD + d0;
    m0 = *(const float4*)(mu);
    m1 = *(const float4*)(mu + 4);
    s0 = *(const float4*)(sg);
    s1 = *(const float4*)(sg + 4);
  }

  // ---- x loads (1 row-tile per wave) ----
  const int base = blockIdx.x * 256 + wave * 16;
  const int rA = base + c1;
  const size_t oA = (size_t)(rA < n ? rA : n - 1) * GD;  // clamp; masked at the sum
  const float4 xA0 = *(const float4*)(x + oA + dlo);
  const float4 xA1 = *(const float4*)(x + oA + dlo + 4);
  const float4 xA2 = *(const float4*)(x + oA + dhi);
  const float4 xA3 = *(const float4*)(x + oA + dhi + 4);

  // ---- cooperative fold (threads 0..255): col c, 8 dims each ----
  if (folder) {
    const float mv[8] = {m0.x, m0.y, m0.z, m0.w, m1.x, m1.y, m1.z, m1.w};
    const float sv[8] = {s0.x, s0.y, s0.z, s0.w, s1.x, s1.y, s1.z, s1.w};
    bf16x8 f1, f2;
    float ls = 0.f, mm = 0.f, pr = 0.f;
#pragma unroll
    for (int j = 0; j < 8; ++j) {
      const float iv = __builtin_amdgcn_rcpf(sv[j] * sv[j]);
      const float l = __logf(sv[j]);
      ls += l;
      mm = fmaf(mv[j] * mv[j], iv, mm);
      f1[j] = f2bf(mv[j] * iv);
      f2[j] = f2bf(-0.5f * iv);
      // prior_mu + prior_sigma element terms (reuses fold registers)
      pr += -0.5f * mv[j] * mv[j] - l - 0.5f * l * l - LOG2PI_F;
    }
    const int gg = gh & 3;
    const int hf = gh >> 2;
    frag[hf][gg][c] = f1;
    frag[hf + 2][gg][c] = f2;
    pls[gh][c] = ls;
    pmm[gh][c] = mm;
    if (blockIdx.x == 0) {
#pragma unroll
      for (int off = 1; off < 64; off <<= 1) pr += __shfl_xor(pr, off);
      if (lane == 0) pprior[wave] = pr;
    }
  }
  __syncthreads();
  if (t < GK) {
    float ls = 0.f, mm = 0.f;
#pragma unroll
    for (int i = 0; i < 8; ++i) { ls += pls[i][t]; mm += pmm[i][t]; }
    const float lp = __logf(theta[t]);
    Asm[t] = lp - ls - 0.5f * GD * LOG2PI_F - 0.5f * mm;
    if (blockIdx.x == 0) {
      float plp = 999.0f * lp;  // (ALPHA0-1) * log p[k]
#pragma unroll
      for (int off = 1; off < 32; off <<= 1) plp += __shfl_xor(plp, off);
      if (t == 0) pprior[4] = plp;
    }
  }
  __syncthreads();

  // ---- weights = A-operands, register-resident ----
  const bf16x8 W0l = frag[0][g][c1], W0h = frag[0][g][c1 + 16];
  const bf16x8 W1l = frag[1][g][c1], W1h = frag[1][g][c1 + 16];
  const bf16x8 W2l = frag[2][g][c1], W2h = frag[2][g][c1 + 16];
  const bf16x8 W3l = frag[3][g][c1], W3h = frag[3][g][c1 + 16];
  float asl[4], ash[4];
#pragma unroll
  for (int j = 0; j < 4; ++j) {
    asl[j] = Asm[g * 4 + j];
    ash[j] = Asm[16 + g * 4 + j];
  }

  // ---- B-fragments + 8 MFMAs ----
  const bf16x8 b0 = pack8(xA0, xA1);
  const bf16x8 b1 = pack8(xA2, xA3);
  const bf16x8 b2 = pack8(sq4(xA0), sq4(xA1));
  const bf16x8 b3 = pack8(sq4(xA2), sq4(xA3));
  f32x4 D0 = {0.f, 0.f, 0.f, 0.f};
  f32x4 D1 = {0.f, 0.f, 0.f, 0.f};
  D0 = __builtin_amdgcn_mfma_f32_16x16x32_bf16(W0l, b0, D0, 0, 0, 0);
  D1 = __builtin_amdgcn_mfma_f32_16x16x32_bf16(W0h, b0, D1, 0, 0, 0);
  D0 = __builtin_amdgcn_mfma_f32_16x16x32_bf16(W1l, b1, D0, 0, 0, 0);
  D1 = __builtin_amdgcn_mfma_f32_16x16x32_bf16(W1h, b1, D1, 0, 0, 0);
  D0 = __builtin_amdgcn_mfma_f32_16x16x32_bf16(W2l, b2, D0, 0, 0, 0);
  D1 = __builtin_amdgcn_mfma_f32_16x16x32_bf16(W2h, b2, D1, 0, 0, 0);
  D0 = __builtin_amdgcn_mfma_f32_16x16x32_bf16(W3l, b3, D0, 0, 0, 0);
  D1 = __builtin_amdgcn_mfma_f32_16x16x32_bf16(W3h, b3, D1, 0, 0, 0);

  // ---- lane-local LSE (8 comps/lane), cross-g combine via 2+2 shuffles ----
  const float e0 = D0[0] + asl[0], e1 = D0[1] + asl[1];
  const float e2 = D0[2] + asl[2], e3 = D0[3] + asl[3];
  const float e4 = D1[0] + ash[0], e5 = D1[1] + ash[1];
  const float e6 = D1[2] + ash[2], e7 = D1[3] + ash[3];
  float m = fmaxf(fmaxf(fmaxf(e0, e1), fmaxf(e2, e3)),
                  fmaxf(fmaxf(e4, e5), fmaxf(e6, e7)));
  m = fmaxf(m, __shfl_xor(m, 16));
  m = fmaxf(m, __shfl_xor(m, 32));
  float e = (__expf(e0 - m) + __expf(e1 - m)) + (__expf(e2 - m) + __expf(e3 - m)) +
            (__expf(e4 - m) + __expf(e5 - m)) + (__expf(e6 - m) + __expf(e7 - m));
  e += __shfl_xor(e, 16);
  e += __shfl_xor(e, 32);
  const float lA = m + __logf(e);

  // ---- block reduction: g==0 lanes hold complete per-row LSEs ----
  float v = (g == 0 && rA < n) ? lA : 0.f;
  v += __shfl_xor(v, 1);
  v += __shfl_xor(v, 2);
  v += __shfl_xor(v, 4);
  v += __shfl_xor(v, 8);
  if (lane == 0) bred[wave] = v;
  __syncthreads();
  if (t == 0) {
    float s = 0.f;
#pragma unroll
    for (int i = 0; i < 16; ++i) s += bred[i];
    ws[blockIdx.x] = s;
    if (blockIdx.x == 0)
      ws[nblk] = (pprior[0] + pprior[1]) + (pprior[2] + pprior[3]) + pprior[4];
  }
}

// Tiny tail: sum 196 partials, scale, add priors (ws[nblk]) + gterm, write out.
__global__ __launch_bounds__(256) void gmm_tail(const int* __restrict__ fds,
                                                const float* __restrict__ ws,
                                                float* __restrict__ out,
                                                float gterm, int n, int nblk) {
  const int t = threadIdx.x;
  float acc = (t < nblk) ? ws[t] : 0.f;
  acc *= (float)fds[0] / (float)n;
  if (t == 0) acc += ws[nblk] + gterm;
#pragma unroll
  for (int off = 1; off < 64; off <<= 1) acc += __shfl_xor(acc, off);
  __shared__ float red[4];
  if ((t & 63) == 0) red[t >> 6] = acc;
  __syncthreads();
  if (t == 0) out[0] = (red[0] + red[1]) + (red[2] + red[3]);
}
}  // namespace

extern "C" void kernel_launch(void* const* d_in, const int* in_sizes, int n_in,
                              void* d_out, int out_size, void* d_ws, size_t ws_size,
                              hipStream_t stream) {
  const float* x = (const float*)d_in[0];
  const float* theta = (const float*)d_in[1];
  const int* fds = (const int*)d_in[2];
  float* out = (float*)d_out;
  float* ws = (float*)d_ws;
  const int n = in_sizes[0] / GD;     // 50000
  const int nblk = (n + 255) / 256;   // 256 rows/block -> 196 blocks, 1024 thr each
  // gammaln(K*a) - K*gammaln(a): constant of the problem shape, computed on HOST
  const float gterm = (float)(lgamma(32.0 * 1000.0) - 32.0 * lgamma(1000.0));

  gmm_main<<<nblk, 1024, 0, stream>>>(x, theta, ws, n, nblk);
  gmm_tail<<<1, 256, 0, stream>>>(fds, ws, out, gterm, n, nblk);
}